// Round 3
// baseline (88.428 us; speedup 1.0000x reference)
//
#include <hip/hip_runtime.h>
#include <hip/hip_bf16.h>

// Problem constants
#define B_    32
#define M_    1024
#define H_    128
#define SPAN_ 1024
#define KL_   2048
#define NITER 17
#define SCALE 0.08838834764831845f

typedef __attribute__((ext_vector_type(8))) short bf16x8;
typedef __attribute__((ext_vector_type(4))) float f32x4;

// ---- workspace layout (bf16, tile-contiguous, pre-swizzled) ----
// tiles are 16 KB: A-type [64 rows][256 B], 16B-unit u stored at u^(row&7)
//                  V-type [128 rows][128 B], unit u stored at u^(row&7)
#define QOFF 0ull           // 32*16 tiles
#define KOFF 8388608ull     // 32*32 tiles
#define VOFF 25165824ull    // 32*32 tiles
#define POFF 41943040ull    // 16 tiles
#define WSNEED 42205184ull

static __device__ __forceinline__ unsigned int cvt_pk2(float lo, float hi) {
  unsigned int r;
  asm("v_cvt_pk_bf16_f32 %0, %1, %2" : "=v"(r) : "v"(lo), "v"(hi));
  return r;
}
static __device__ __forceinline__ unsigned short f2b(float x) {
  unsigned int u = __builtin_bit_cast(unsigned int, x);
  return (unsigned short)((u + 0x7FFFu + ((u >> 16) & 1u)) >> 16);
}
static __device__ __forceinline__ float b2f(unsigned short u) {
  return __builtin_bit_cast(float, ((unsigned int)u) << 16);
}
static __device__ __forceinline__ bf16x8 ldfrag(const char* p) {  // 8B-aligned fallback
  short4 a = *(const short4*)p;
  short4 b = *(const short4*)(p + 8);
  bf16x8 r;
  r[0] = a.x; r[1] = a.y; r[2] = a.z; r[3] = a.w;
  r[4] = b.x; r[5] = b.y; r[6] = b.z; r[7] = b.w;
  return r;
}
static __device__ __forceinline__ void gll16(char* lds, const char* g) {
  __builtin_amdgcn_global_load_lds(
      (const __attribute__((address_space(1))) unsigned int*)g,
      (__attribute__((address_space(3))) unsigned int*)lds, 16, 0, 0);
}

// ======================= pre-conversion kernels =======================
__global__ void convA(const float* __restrict__ in, char* __restrict__ out,
                      int nunits, float scale) {
  int idx = blockIdx.x * 256 + threadIdx.x;
  if (idx >= nunits) return;
  int r = idx >> 4, u = idx & 15;
  const float* p = in + (size_t)r * 128 + u * 8;
  float4 a = *(const float4*)p, b = *(const float4*)(p + 4);
  uint4 d;
  d.x = cvt_pk2(a.x * scale, a.y * scale);
  d.y = cvt_pk2(a.z * scale, a.w * scale);
  d.z = cvt_pk2(b.x * scale, b.y * scale);
  d.w = cvt_pk2(b.z * scale, b.w * scale);
  *(uint4*)(out + (size_t)r * 256 + 16 * (u ^ (r & 7))) = d;
}

__global__ void convV(const float* __restrict__ v, char* __restrict__ out) {
  __shared__ float tile[64][130];
  int tb = blockIdx.x;  // b*32 + kt
  const float* src = v + (size_t)tb * 64 * 128;
  int tid = threadIdx.x;
#pragma unroll
  for (int i = 0; i < 8; ++i) {
    int idx = i * 256 + tid;
    int row = idx >> 5, c4 = idx & 31;
    float4 x = *(const float4*)(src + row * 128 + c4 * 4);
    tile[row][c4 * 4 + 0] = x.x; tile[row][c4 * 4 + 1] = x.y;
    tile[row][c4 * 4 + 2] = x.z; tile[row][c4 * 4 + 3] = x.w;
  }
  __syncthreads();
  char* dst = out + (size_t)tb * 16384;
#pragma unroll
  for (int j = 0; j < 4; ++j) {
    int idx = j * 256 + tid;
    int h = idx >> 3, u = idx & 7;
    uint4 d;
    d.x = cvt_pk2(tile[8 * u + 0][h], tile[8 * u + 1][h]);
    d.y = cvt_pk2(tile[8 * u + 2][h], tile[8 * u + 3][h]);
    d.z = cvt_pk2(tile[8 * u + 4][h], tile[8 * u + 5][h]);
    d.w = cvt_pk2(tile[8 * u + 6][h], tile[8 * u + 7][h]);
    *(uint4*)(dst + h * 128 + 16 * (u ^ (h & 7))) = d;
  }
}

__global__ void convP(const float* __restrict__ pe, char* __restrict__ out) {
  __shared__ float tile[128][66];
  int lt = blockIdx.x, tid = threadIdx.x;
#pragma unroll
  for (int i = 0; i < 8; ++i) {
    int idx = i * 256 + tid;
    int h = idx >> 4, c4 = idx & 15;
    float4 x = *(const float4*)(pe + (size_t)h * 1024 + lt * 64 + c4 * 4);
    tile[h][c4 * 4 + 0] = x.x; tile[h][c4 * 4 + 1] = x.y;
    tile[h][c4 * 4 + 2] = x.z; tile[h][c4 * 4 + 3] = x.w;
  }
  __syncthreads();
  char* dst = out + (size_t)lt * 16384;
#pragma unroll
  for (int j = 0; j < 4; ++j) {
    int idx = j * 256 + tid;
    int l = idx >> 4, u = idx & 15;
    uint4 d;
    d.x = cvt_pk2(tile[8 * u + 0][l], tile[8 * u + 1][l]);
    d.y = cvt_pk2(tile[8 * u + 2][l], tile[8 * u + 3][l]);
    d.z = cvt_pk2(tile[8 * u + 4][l], tile[8 * u + 5][l]);
    d.w = cvt_pk2(tile[8 * u + 6][l], tile[8 * u + 7][l]);
    *(uint4*)(dst + l * 256 + 16 * (u ^ (l & 7))) = d;
  }
}

// ======================= main kernel (bf16 ws path) =======================
// LDS: KL 16K | VT 16K | PT 16K | PR 16896 | PW 8704  = 74752 -> 2 blocks/CU
#define L_KL 0
#define L_VT 16384
#define L_PT 32768
#define L_PR 49152
#define L_PW 66048
#define LDS_MAIN 74752

__global__ void __launch_bounds__(256, 2) seqattn_main(
    const char* __restrict__ qws, const char* __restrict__ kws,
    const char* __restrict__ vws, const char* __restrict__ pws,
    float* __restrict__ out) {
  extern __shared__ char smem[];
  char* KL = smem + L_KL;
  char* VT = smem + L_VT;
  char* PT = smem + L_PT;
  char* PR = smem + L_PR;
  char* PW = smem + L_PW;

  int jb = blockIdx.x;
  int o  = (jb & 7) * 64 + (jb >> 3);
  int b  = o >> 4;
  int m0t = o & 15;

  int tid = threadIdx.x, w = tid >> 6, lane = tid & 63, g = lane >> 4, c = lane & 15;
  int mrow = 16 * w + c;
  int sx = c & 7;
  int foffA[4], foffV[2];
#pragma unroll
  for (int hs = 0; hs < 4; ++hs) foffA[hs] = 16 * (((hs << 2) | g) ^ sx);
  foffV[0] = 16 * (g ^ sx);
  foffV[1] = 16 * ((4 | g) ^ sx);

  const char* qsrc = qws + ((size_t)(b * 16 + m0t)) * 16384;
  const char* ksrc = kws + ((size_t)(b * 32 + m0t)) * 16384;
  const char* vsrc = vws + ((size_t)(b * 32 + m0t)) * 16384;

  // ---- stage Q into KL, read fragments ----
#pragma unroll
  for (int i = 0; i < 4; ++i)
    gll16(KL + (4 * w + i) * 1024, qsrc + (4 * w + i) * 1024 + lane * 16);
  __syncthreads();
  bf16x8 qf[4];
#pragma unroll
  for (int hs = 0; hs < 4; ++hs)
    qf[hs] = *(const bf16x8*)(KL + mrow * 256 + foffA[hs]);
  __syncthreads();
  // ---- stage tiles for t=0 ----
#pragma unroll
  for (int i = 0; i < 4; ++i) {
    gll16(KL + (4 * w + i) * 1024, ksrc + (4 * w + i) * 1024 + lane * 16);
    gll16(VT + (4 * w + i) * 1024, vsrc + (4 * w + i) * 1024 + lane * 16);
    gll16(PT + (4 * w + i) * 1024, pws + (4 * w + i) * 1024 + lane * 16);
  }
  __syncthreads();

  f32x4 O[8];
#pragma unroll
  for (int i = 0; i < 8; ++i) { O[i][0] = 0.f; O[i][1] = 0.f; O[i][2] = 0.f; O[i][3] = 0.f; }
  float mrun = -1e30f, lrun = 0.f;
  char* prRow = PR + mrow * 264;
  char* pwRow = PW + mrow * 136;

#pragma unroll 1
  for (int t = 0; t < NITER; ++t) {
    // ---- bias chunk: lane gets bias[mrow][l=64t+16lt+4g+rr] ----
    if (t < 16) {
#pragma unroll
      for (int lt = 0; lt < 4; ++lt) {
        f32x4 pb = {0.f, 0.f, 0.f, 0.f};
#pragma unroll
        for (int hs = 0; hs < 4; ++hs)
          pb = __builtin_amdgcn_mfma_f32_16x16x32_bf16(
              *(const bf16x8*)(PT + (16 * lt + c) * 256 + foffA[hs]), qf[hs], pb, 0, 0, 0);
#pragma unroll
        for (int rr = 0; rr < 4; ++rr) {
          int x = (64 * t + 16 * lt + 4 * g + rr + mrow) & 127;
          *(unsigned short*)(prRow + x * 2) = f2b(pb[rr]);
        }
      }
    }
    // ---- S^T = K Q^T ----
    f32x4 s[4];
#pragma unroll
    for (int nt = 0; nt < 4; ++nt) {
      f32x4 acc = {0.f, 0.f, 0.f, 0.f};
#pragma unroll
      for (int hs = 0; hs < 4; ++hs)
        acc = __builtin_amdgcn_mfma_f32_16x16x32_bf16(
            *(const bf16x8*)(KL + (16 * nt + c) * 256 + foffA[hs]), qf[hs], acc, 0, 0, 0);
      s[nt] = acc;
    }
    // ---- V fragments -> registers (frees VT for reload) ----
    bf16x8 vf[16];
#pragma unroll
    for (int nt = 0; nt < 8; ++nt)
#pragma unroll
      for (int ks = 0; ks < 2; ++ks)
        vf[nt * 2 + ks] = *(const bf16x8*)(VT + (16 * nt + c) * 128 + foffV[ks]);

    __syncthreads();  // barrier1: KL/PT/VT all dead -> reload
    if (t < 16) {
      const char* ks_ = ksrc + (size_t)(t + 1) * 16384;
      const char* vs_ = vsrc + (size_t)(t + 1) * 16384;
#pragma unroll
      for (int i = 0; i < 4; ++i) {
        gll16(KL + (4 * w + i) * 1024, ks_ + (4 * w + i) * 1024 + lane * 16);
        gll16(VT + (4 * w + i) * 1024, vs_ + (4 * w + i) * 1024 + lane * 16);
      }
      if (t < 15) {
        const char* ps_ = pws + (size_t)(t + 1) * 16384;
#pragma unroll
        for (int i = 0; i < 4; ++i)
          gll16(PT + (4 * w + i) * 1024, ps_ + (4 * w + i) * 1024 + lane * 16);
      }
    }

    // ---- bias add (ring b64 reads) + band mask ----
#pragma unroll
    for (int nt = 0; nt < 4; ++nt) {
      int x = (64 * t + 16 * nt + 4 * g) & 127;
      ushort4 bv = *(const ushort4*)(prRow + x * 2);
      int lbase = 64 * t + 16 * nt + 4 * g - mrow;
      const unsigned short* bp = (const unsigned short*)&bv;
#pragma unroll
      for (int rr = 0; rr < 4; ++rr) {
        float sv = s[nt][rr] + b2f(bp[rr]);
        s[nt][rr] = ((unsigned)(lbase + rr) < 1024u) ? sv : -1e30f;
      }
    }
    // ---- online softmax (defer-max) ----
    float pmax = -1e30f;
#pragma unroll
    for (int nt = 0; nt < 4; ++nt)
#pragma unroll
      for (int rr = 0; rr < 4; ++rr) pmax = fmaxf(pmax, s[nt][rr]);
    pmax = fmaxf(pmax, __shfl_xor(pmax, 16, 64));
    pmax = fmaxf(pmax, __shfl_xor(pmax, 32, 64));
    if (__any(pmax > mrun + 8.0f)) {
      float mn = fmaxf(mrun, pmax);
      float corr = __expf(mrun - mn);
      mrun = mn;
      lrun *= corr;
#pragma unroll
      for (int i = 0; i < 8; ++i) {
        O[i][0] *= corr; O[i][1] *= corr; O[i][2] *= corr; O[i][3] *= corr;
      }
    }
    float rsum = 0.f;
#pragma unroll
    for (int nt = 0; nt < 4; ++nt) {
      float p0 = __expf(s[nt][0] - mrun);
      float p1 = __expf(s[nt][1] - mrun);
      float p2 = __expf(s[nt][2] - mrun);
      float p3 = __expf(s[nt][3] - mrun);
      rsum += (p0 + p1) + (p2 + p3);
      uint2 d_;
      d_.x = cvt_pk2(p0, p1);
      d_.y = cvt_pk2(p2, p3);
      *(uint2*)(pwRow + (16 * nt + 4 * g) * 2) = d_;
    }
    rsum += __shfl_xor(rsum, 16, 64);
    rsum += __shfl_xor(rsum, 32, 64);
    lrun += rsum;
    // ---- O^T += V^T P^T (V from regs) ----
#pragma unroll
    for (int ks = 0; ks < 2; ++ks) {
      bf16x8 pfrag = ldfrag(pwRow + ks * 64 + g * 16);
#pragma unroll
      for (int nt = 0; nt < 8; ++nt)
        O[nt] = __builtin_amdgcn_mfma_f32_16x16x32_bf16(
            vf[nt * 2 + ks], pfrag, O[nt], 0, 0, 0);
    }
    __syncthreads();  // barrier2: drains global_load_lds -> t+1 tiles ready
  }

  float inv = 1.0f / lrun;
  float* ob = out + ((size_t)b * M_ + m0t * 64 + mrow) * H_;
#pragma unroll
  for (int nt = 0; nt < 8; ++nt) {
    float4 vv;
    vv.x = O[nt][0] * inv; vv.y = O[nt][1] * inv;
    vv.z = O[nt][2] * inv; vv.w = O[nt][3] * inv;
    *(float4*)(ob + 16 * nt + 4 * g) = vv;
  }
}

// ======================= fallback (round-2 kernel, f32 in-kernel staging) ==
#define PITCH_A  264
#define PITCH_VT 136
#define PITCH_PR 264
#define PITCH_PW 136
#define OFF_K  0
#define OFF_VT 16896
#define OFF_PT 34304
#define OFF_PR 51200
#define OFF_PW 68096
#define LDS_FB 76800

__global__ void __launch_bounds__(256, 2) seqattn_fb(
    const float* __restrict__ q, const float* __restrict__ kkey,
    const float* __restrict__ vval, const float* __restrict__ pe,
    float* __restrict__ out) {
  extern __shared__ char smem[];
  char* KL = smem + OFF_K;
  char* VT = smem + OFF_VT;
  char* PT = smem + OFF_PT;
  char* PR = smem + OFF_PR;
  char* PW = smem + OFF_PW;

  int jb = blockIdx.x;
  int o  = (jb & 7) * 64 + (jb >> 3);
  int b  = o >> 4;
  int m0 = (o & 15) * 64;

  int tid  = threadIdx.x;
  int w    = tid >> 6;
  int lane = tid & 63;
  int g    = lane >> 4;
  int c    = lane & 15;
  int r0   = tid >> 5;
  int c4   = tid & 31;

  const float* qbase = q    + ((size_t)b * M_  + m0) * H_;
  const float* kbase = kkey + ((size_t)b * KL_ + m0) * H_;
  const float* vbase = vval + ((size_t)b * KL_ + m0) * H_;

  float4 kpre[8];
  float  vpre[32];
  float  ppre[32];

#define LOADK(tt) do {                                                        \
    const float* kb_ = kbase + (size_t)(64 * (tt)) * H_;                      \
    _Pragma("unroll")                                                         \
    for (int p = 0; p < 8; ++p)                                               \
      kpre[p] = *(const float4*)(kb_ + (p * 8 + r0) * H_ + c4 * 4);           \
  } while (0)
#define WRITEK() do {                                                         \
    _Pragma("unroll")                                                         \
    for (int p = 0; p < 8; ++p) {                                             \
      float4 v_ = kpre[p];                                                    \
      uint2 d_; d_.x = cvt_pk2(v_.x, v_.y); d_.y = cvt_pk2(v_.z, v_.w);       \
      *(uint2*)(KL + (p * 8 + r0) * PITCH_A + c4 * 8) = d_;                   \
    }                                                                         \
  } while (0)
#define LOADV(tt) do {                                                        \
    const float* vb_ = vbase + (size_t)(64 * (tt)) * H_;                      \
    _Pragma("unroll")                                                         \
    for (int qq = 0; qq < 4; ++qq) {                                          \
      int kq_ = 4 * (4 * w + qq);                                             \
      _Pragma("unroll")                                                       \
      for (int r = 0; r < 4; ++r) {                                           \
        vpre[qq * 8 + r * 2 + 0] = vb_[(kq_ + r) * H_ + lane];                \
        vpre[qq * 8 + r * 2 + 1] = vb_[(kq_ + r) * H_ + lane + 64];           \
      }                                                                       \
    }                                                                         \
  } while (0)
#define WRITEV() do {                                                         \
    _Pragma("unroll")                                                         \
    for (int qq = 0; qq < 4; ++qq) {                                          \
      int kq_ = 4 * w + qq;                                                   \
      uint2 lo_, hi_;                                                         \
      lo_.x = cvt_pk2(vpre[qq * 8 + 0], vpre[qq * 8 + 2]);                    \
      lo_.y = cvt_pk2(vpre[qq * 8 + 4], vpre[qq * 8 + 6]);                    \
      hi_.x = cvt_pk2(vpre[qq * 8 + 1], vpre[qq * 8 + 3]);                    \
      hi_.y = cvt_pk2(vpre[qq * 8 + 5], vpre[qq * 8 + 7]);                    \
      *(uint2*)(VT + lane * PITCH_VT + 8 * kq_) = lo_;                        \
      *(uint2*)(VT + (lane + 64) * PITCH_VT + 8 * kq_) = hi_;                 \
    }                                                                         \
  } while (0)
#define LOADP(tt) do {                                                        \
    const float* pb_ = pe + 64 * (tt);                                        \
    _Pragma("unroll")                                                         \
    for (int qq = 0; qq < 8; ++qq) {                                          \
      int h_ = 4 * (8 * w + qq);                                              \
      _Pragma("unroll")                                                       \
      for (int r = 0; r < 4; ++r)                                             \
        ppre[qq * 4 + r] = pb_[(h_ + r) * SPAN_ + lane];                      \
    }                                                                         \
  } while (0)
#define WRITEP() do {                                                         \
    _Pragma("unroll")                                                         \
    for (int qq = 0; qq < 8; ++qq) {                                          \
      uint2 d_;                                                               \
      d_.x = cvt_pk2(ppre[qq * 4 + 0], ppre[qq * 4 + 1]);                     \
      d_.y = cvt_pk2(ppre[qq * 4 + 2], ppre[qq * 4 + 3]);                     \
      *(uint2*)(PT + lane * PITCH_A + 8 * (8 * w + qq)) = d_;                 \
    }                                                                         \
  } while (0)

  {
    float4 qpre[8];
#pragma unroll
    for (int p = 0; p < 8; ++p)
      qpre[p] = *(const float4*)(qbase + (p * 8 + r0) * H_ + c4 * 4);
    LOADK(0); LOADV(0); LOADP(0);
#pragma unroll
    for (int p = 0; p < 8; ++p) {
      float4 v_ = qpre[p];
      uint2 d_;
      d_.x = cvt_pk2(v_.x * SCALE, v_.y * SCALE);
      d_.y = cvt_pk2(v_.z * SCALE, v_.w * SCALE);
      *(uint2*)(PR + (p * 8 + r0) * PITCH_PR + c4 * 8) = d_;
    }
    WRITEK(); WRITEV(); WRITEP();
    LOADK(1); LOADV(1); LOADP(1);
  }
  __syncthreads();

  bf16x8 qf[4];
#pragma unroll
  for (int hs = 0; hs < 4; ++hs)
    qf[hs] = ldfrag(PR + (w * 16 + c) * PITCH_PR + hs * 64 + g * 16);

  f32x4 O[8];
#pragma unroll
  for (int i = 0; i < 8; ++i) { O[i][0] = 0.f; O[i][1] = 0.f; O[i][2] = 0.f; O[i][3] = 0.f; }
  float mrun = -1e30f, lrun = 0.f;
  const int mrow = 16 * w + c;
  char* prRow = PR + mrow * PITCH_PR;
  char* pwRow = PW + mrow * PITCH_PW;

#pragma unroll 1
  for (int t = 0; t < NITER; ++t) {
    if (t < 16) {
#pragma unroll
      for (int lt = 0; lt < 4; ++lt) {
        f32x4 pb = {0.f, 0.f, 0.f, 0.f};
#pragma unroll
        for (int hs = 0; hs < 4; ++hs)
          pb = __builtin_amdgcn_mfma_f32_16x16x32_bf16(
              ldfrag(PT + (16 * lt + c) * PITCH_A + hs * 64 + g * 16), qf[hs], pb, 0, 0, 0);
#pragma unroll
        for (int rr = 0; rr < 4; ++rr) {
          int x = (64 * t + 16 * lt + 4 * g + rr + mrow) & 127;
          *(unsigned short*)(prRow + x * 2) = f2b(pb[rr]);
        }
      }
    }
    f32x4 s[4];
#pragma unroll
    for (int nt = 0; nt < 4; ++nt) {
      f32x4 acc = {0.f, 0.f, 0.f, 0.f};
#pragma unroll
      for (int hs = 0; hs < 4; ++hs)
        acc = __builtin_amdgcn_mfma_f32_16x16x32_bf16(
            ldfrag(KL + (16 * nt + c) * PITCH_A + hs * 64 + g * 16), qf[hs], acc, 0, 0, 0);
      s[nt] = acc;
    }
#pragma unroll
    for (int nt = 0; nt < 4; ++nt) {
      int x = (64 * t + 16 * nt + 4 * g) & 127;
      ushort4 bv = *(const ushort4*)(prRow + x * 2);
      int lbase = 64 * t + 16 * nt + 4 * g - mrow;
      const unsigned short* bp = (const unsigned short*)&bv;
#pragma unroll
      for (int rr = 0; rr < 4; ++rr) {
        float sv = s[nt][rr] + b2f(bp[rr]);
        s[nt][rr] = ((unsigned)(lbase + rr) < 1024u) ? sv : -1e30f;
      }
    }
    float pmax = -1e30f;
#pragma unroll
    for (int nt = 0; nt < 4; ++nt)
#pragma unroll
      for (int rr = 0; rr < 4; ++rr) pmax = fmaxf(pmax, s[nt][rr]);
    pmax = fmaxf(pmax, __shfl_xor(pmax, 16, 64));
    pmax = fmaxf(pmax, __shfl_xor(pmax, 32, 64));
    if (__any(pmax > mrun + 8.0f)) {
      float mn = fmaxf(mrun, pmax);
      float corr = __expf(mrun - mn);
      mrun = mn;
      lrun *= corr;
#pragma unroll
      for (int i = 0; i < 8; ++i) {
        O[i][0] *= corr; O[i][1] *= corr; O[i][2] *= corr; O[i][3] *= corr;
      }
    }
    float rsum = 0.f;
#pragma unroll
    for (int nt = 0; nt < 4; ++nt) {
      float p0 = __expf(s[nt][0] - mrun);
      float p1 = __expf(s[nt][1] - mrun);
      float p2 = __expf(s[nt][2] - mrun);
      float p3 = __expf(s[nt][3] - mrun);
      rsum += (p0 + p1) + (p2 + p3);
      uint2 d_;
      d_.x = cvt_pk2(p0, p1);
      d_.y = cvt_pk2(p2, p3);
      *(uint2*)(pwRow + (16 * nt + 4 * g) * 2) = d_;
    }
    rsum += __shfl_xor(rsum, 16, 64);
    rsum += __shfl_xor(rsum, 32, 64);
    lrun += rsum;
#pragma unroll
    for (int ks = 0; ks < 2; ++ks) {
      bf16x8 pfrag = ldfrag(pwRow + ks * 64 + g * 16);
#pragma unroll
      for (int nt = 0; nt < 8; ++nt)
        O[nt] = __builtin_amdgcn_mfma_f32_16x16x32_bf16(
            ldfrag(VT + (16 * nt + c) * PITCH_VT + ks * 64 + g * 16), pfrag, O[nt], 0, 0, 0);
    }
    __syncthreads();
    if (t < 16) {
      WRITEK(); WRITEV();
      if (t < 15) {
        WRITEP();
        LOADK(t + 2); LOADV(t + 2);
        if (t + 2 < 16) LOADP(t + 2);
      }
    }
    __syncthreads();
  }

  float inv = 1.0f / lrun;
  float* ob = out + ((size_t)b * M_ + m0 + mrow) * H_;
#pragma unroll
  for (int nt = 0; nt < 8; ++nt) {
    float4 vv;
    vv.x = O[nt][0] * inv; vv.y = O[nt][1] * inv;
    vv.z = O[nt][2] * inv; vv.w = O[nt][3] * inv;
    *(float4*)(ob + 16 * nt + 4 * g) = vv;
  }
}
#undef LOADK
#undef WRITEK
#undef LOADV
#undef WRITEV
#undef LOADP
#undef WRITEP

extern "C" void kernel_launch(void* const* d_in, const int* in_sizes, int n_in,
                              void* d_out, int out_size, void* d_ws, size_t ws_size,
                              hipStream_t stream) {
  const float* q  = (const float*)d_in[0];
  const float* k  = (const float*)d_in[1];
  const float* v  = (const float*)d_in[2];
  const float* pe = (const float*)d_in[3];
  float* out = (float*)d_out;

  if (ws_size >= WSNEED) {
    char* ws = (char*)d_ws;
    convA<<<dim3(2048), dim3(256), 0, stream>>>(q, ws + QOFF, 32 * 1024 * 16, SCALE);
    convA<<<dim3(4096), dim3(256), 0, stream>>>(k, ws + KOFF, 32 * 2048 * 16, 1.0f);
    convV<<<dim3(1024), dim3(256), 0, stream>>>(v, ws + VOFF);
    convP<<<dim3(16), dim3(256), 0, stream>>>(pe, ws + POFF);
    hipFuncSetAttribute(reinterpret_cast<const void*>(seqattn_main),
                        hipFuncAttributeMaxDynamicSharedMemorySize, LDS_MAIN);
    seqattn_main<<<dim3(512), dim3(256), LDS_MAIN, stream>>>(
        ws + QOFF, ws + KOFF, ws + VOFF, ws + POFF, out);
  } else {
    hipFuncSetAttribute(reinterpret_cast<const void*>(seqattn_fb),
                        hipFuncAttributeMaxDynamicSharedMemorySize, LDS_FB);
    seqattn_fb<<<dim3(512), dim3(256), LDS_FB, stream>>>(q, k, v, pe, out);
  }
}